// Round 1
// baseline (499.630 us; speedup 1.0000x reference)
//
#include <hip/hip_runtime.h>
#include <math.h>

#define NN 10000
#define NE 160000
#define SCALE_F 0.17677669529663687f

// ---------------- CSR build ----------------
__global__ __launch_bounds__(256) void zero_kernel(int* __restrict__ p, int n) {
  int i = blockIdx.x * 256 + threadIdx.x;
  if (i < n) p[i] = 0;
}

__global__ __launch_bounds__(256) void hist_kernel(const int* __restrict__ dst, int* __restrict__ counts) {
  int e = blockIdx.x * 256 + threadIdx.x;
  if (e < NE) atomicAdd(&counts[dst[e]], 1);
}

__global__ __launch_bounds__(1024) void scan_kernel(int* __restrict__ counts, int* __restrict__ row_start) {
  __shared__ int part[1024];
  int tid = threadIdx.x;
  const int PER = 10; // 1024*10 >= 10000
  int base = tid * PER;
  int loc[PER];
  int sum = 0;
#pragma unroll
  for (int i = 0; i < PER; ++i) {
    int idx = base + i;
    int c = (idx < NN) ? counts[idx] : 0;
    loc[i] = sum;
    sum += c;
  }
  part[tid] = sum;
  __syncthreads();
  for (int off = 1; off < 1024; off <<= 1) {
    int t = (tid >= off) ? part[tid - off] : 0;
    __syncthreads();
    part[tid] += t;
    __syncthreads();
  }
  int offset = (tid > 0) ? part[tid - 1] : 0;
#pragma unroll
  for (int i = 0; i < PER; ++i) {
    int idx = base + i;
    if (idx < NN) {
      int st = offset + loc[i];
      row_start[idx] = st;
      counts[idx] = st; // counts becomes the scatter cursor
    }
  }
  if (tid == 1023) row_start[NN] = part[1023];
}

__global__ __launch_bounds__(256) void scatter_kernel(const int* __restrict__ src, const int* __restrict__ dst,
                                                      const float* __restrict__ obs, int* __restrict__ cursor,
                                                      int* __restrict__ col_src, float* __restrict__ posw) {
  int e = blockIdx.x * 256 + threadIdx.x;
  if (e >= NE) return;
  int s = src[e], d = dst[e];
  int p = atomicAdd(&cursor[d], 1);
  col_src[p] = s;
  float dx = obs[d * 37 + 0] - obs[s * 37 + 0];
  float dy = obs[d * 37 + 1] - obs[s * 37 + 1];
  posw[p] = __expf(-sqrtf(dx * dx + dy * dy));
}

// ---------------- layer-0 projections ----------------
__global__ __launch_bounds__(256) void proj0_kernel(const float* __restrict__ obs,
                                                    const float* __restrict__ wq, const float* __restrict__ wk,
                                                    const float* __restrict__ wv,
                                                    float* __restrict__ q, float* __restrict__ k, float* __restrict__ v) {
  int t = blockIdx.x * 256 + threadIdx.x;
  if (t >= NN * 512) return;
  int c = t & 511;
  int n = t >> 9;
  const float* orow = obs + n * 37;
  float o[37];
#pragma unroll
  for (int i = 0; i < 37; ++i) o[i] = orow[i];
  float aq = 0.f, ak = 0.f, av = 0.f;
#pragma unroll
  for (int f = 0; f < 12; ++f) aq += o[f] * wq[f * 512 + c];
#pragma unroll
  for (int f = 12; f < 19; ++f) aq += o[30 + f - 12] * wq[f * 512 + c];
#pragma unroll
  for (int f = 0; f < 12; ++f) ak += o[12 + f] * wk[f * 512 + c];
#pragma unroll
  for (int f = 12; f < 16; ++f) ak += o[26 + f - 12] * wk[f * 512 + c];
#pragma unroll
  for (int f = 0; f < 18; ++f) av += o[12 + f] * wv[f * 512 + c];
  q[t] = aq;
  k[t] = ak;
  v[t] = av;
}

// ---------------- fused GAT edge kernel (one wave per node, online softmax) ----------------
__global__ __launch_bounds__(256) void gat_kernel(const float* __restrict__ q, const float* __restrict__ k,
                                                  const float* __restrict__ v, const int* __restrict__ row_start,
                                                  const int* __restrict__ col_src, const float* __restrict__ posw,
                                                  float* __restrict__ out) {
  int wave = threadIdx.x >> 6;
  int lane = threadIdx.x & 63;
  int n = blockIdx.x * 4 + wave;
  if (n >= NN) return;
  int base = n * 512 + lane * 8;
  float4 qa = *(const float4*)(q + base);
  float4 qb = *(const float4*)(q + base + 4);
  float q0 = qa.x * SCALE_F, q1 = qa.y * SCALE_F, q2 = qa.z * SCALE_F, q3 = qa.w * SCALE_F;
  float q4 = qb.x * SCALE_F, q5 = qb.y * SCALE_F, q6 = qb.z * SCALE_F, q7 = qb.w * SCALE_F;
  int s0 = row_start[n], s1 = row_start[n + 1];
  float m = -INFINITY, den = 0.f;
  float o0 = 0.f, o1 = 0.f, o2 = 0.f, o3 = 0.f, o4 = 0.f, o5 = 0.f, o6 = 0.f, o7 = 0.f;
  for (int j = s0; j < s1; ++j) {
    int s = col_src[j];
    float pw = posw[j];
    int sb = s * 512 + lane * 8;
    float4 ka = *(const float4*)(k + sb);
    float4 kb = *(const float4*)(k + sb + 4);
    float dot = q0 * ka.x + q1 * ka.y + q2 * ka.z + q3 * ka.w + q4 * kb.x + q5 * kb.y + q6 * kb.z + q7 * kb.w;
    dot += __shfl_xor(dot, 1);
    dot += __shfl_xor(dot, 2);
    dot += __shfl_xor(dot, 4);
    dot += __shfl_xor(dot, 8);
    float a = dot * pw;
    float mn = fmaxf(m, a);
    float f = __expf(m - mn);
    float w = __expf(a - mn);
    den = den * f + w;
    m = mn;
    float4 va = *(const float4*)(v + sb);
    float4 vb = *(const float4*)(v + sb + 4);
    o0 = o0 * f + w * va.x;
    o1 = o1 * f + w * va.y;
    o2 = o2 * f + w * va.z;
    o3 = o3 * f + w * va.w;
    o4 = o4 * f + w * vb.x;
    o5 = o5 * f + w * vb.y;
    o6 = o6 * f + w * vb.z;
    o7 = o7 * f + w * vb.w;
  }
  float inv = 1.f / (den + 1e-16f);
  float4 ra = make_float4(o0 * inv, o1 * inv, o2 * inv, o3 * inv);
  float4 rb = make_float4(o4 * inv, o5 * inv, o6 * inv, o7 * inv);
  *(float4*)(out + base) = ra;
  *(float4*)(out + base + 4) = rb;
}

// ---------------- generic fp32 tiled GEMM: C = A(MxK) @ B(KxN) (+bias) (+relu) ----------------
// BM=BN=64, BK=16, 256 threads, 4x4 per thread. Requires K%16==0, N%64==0.
__global__ __launch_bounds__(256) void gemm64(const float* __restrict__ A, const float* __restrict__ B,
                                              const float* __restrict__ bias, float* __restrict__ C,
                                              int M, int N, int K, int relu) {
  __shared__ float As[16][64];
  __shared__ float Bs[16][64];
  int tid = threadIdx.x;
  int m0 = blockIdx.x * 64;
  int n0 = blockIdx.y * 64;
  int tm = (tid >> 4) << 2;
  int tn = (tid & 15) << 2;
  int a_m = tid >> 2;
  int a_k = (tid & 3) << 2;
  int b_k = tid >> 4;
  int b_n = (tid & 15) << 2;
  float acc[4][4] = {};
  for (int k0 = 0; k0 < K; k0 += 16) {
    float4 av;
    int gm = m0 + a_m;
    if (gm < M)
      av = *(const float4*)(A + (size_t)gm * K + k0 + a_k);
    else
      av = make_float4(0.f, 0.f, 0.f, 0.f);
    As[a_k + 0][a_m] = av.x;
    As[a_k + 1][a_m] = av.y;
    As[a_k + 2][a_m] = av.z;
    As[a_k + 3][a_m] = av.w;
    float4 bv = *(const float4*)(B + (size_t)(k0 + b_k) * N + n0 + b_n);
    *(float4*)&Bs[b_k][b_n] = bv;
    __syncthreads();
#pragma unroll
    for (int kk = 0; kk < 16; ++kk) {
      float4 a = *(const float4*)&As[kk][tm];
      float4 b = *(const float4*)&Bs[kk][tn];
      acc[0][0] += a.x * b.x; acc[0][1] += a.x * b.y; acc[0][2] += a.x * b.z; acc[0][3] += a.x * b.w;
      acc[1][0] += a.y * b.x; acc[1][1] += a.y * b.y; acc[1][2] += a.y * b.z; acc[1][3] += a.y * b.w;
      acc[2][0] += a.z * b.x; acc[2][1] += a.z * b.y; acc[2][2] += a.z * b.z; acc[2][3] += a.z * b.w;
      acc[3][0] += a.w * b.x; acc[3][1] += a.w * b.y; acc[3][2] += a.w * b.z; acc[3][3] += a.w * b.w;
    }
    __syncthreads();
  }
#pragma unroll
  for (int i = 0; i < 4; ++i) {
    int gm = m0 + tm + i;
    if (gm < M) {
#pragma unroll
      for (int j = 0; j < 4; ++j) {
        float x = acc[i][j];
        if (bias) x += bias[n0 + tn + j];
        if (relu) x = fmaxf(x, 0.f);
        C[(size_t)gm * N + n0 + tn + j] = x;
      }
    }
  }
}

// ---------------- final tiny GEMM: (10000x256) @ (256x2) + b ----------------
__global__ __launch_bounds__(256) void final_kernel(const float* __restrict__ X, const float* __restrict__ w3,
                                                    const float* __restrict__ b3, float* __restrict__ out) {
  int n = blockIdx.x * 256 + threadIdx.x;
  if (n >= NN) return;
  float a0 = b3[0], a1 = b3[1];
  const float* xr = X + n * 256;
#pragma unroll 8
  for (int j = 0; j < 256; ++j) {
    float x = xr[j];
    a0 += x * w3[j * 2 + 0];
    a1 += x * w3[j * 2 + 1];
  }
  out[n * 2 + 0] = a0;
  out[n * 2 + 1] = a1;
}

extern "C" void kernel_launch(void* const* d_in, const int* in_sizes, int n_in,
                              void* d_out, int out_size, void* d_ws, size_t ws_size,
                              hipStream_t stream) {
  const float* obs = (const float*)d_in[0];
  const int* eidx = (const int*)d_in[1];
  const float* wq0 = (const float*)d_in[2];
  const float* wk0 = (const float*)d_in[3];
  const float* wv0 = (const float*)d_in[4];
  const float* wo0 = (const float*)d_in[5];
  const float* bo0 = (const float*)d_in[6];
  const float* wq1 = (const float*)d_in[7];
  const float* wk1 = (const float*)d_in[8];
  const float* wv1 = (const float*)d_in[9];
  const float* wo1 = (const float*)d_in[10];
  const float* bo1 = (const float*)d_in[11];
  const float* w1 = (const float*)d_in[12];
  const float* b1 = (const float*)d_in[13];
  const float* w2 = (const float*)d_in[14];
  const float* b2 = (const float*)d_in[15];
  const float* w3 = (const float*)d_in[16];
  const float* b3 = (const float*)d_in[17];
  float* outp = (float*)d_out;

  char* wsb = (char*)d_ws;
  float* q = (float*)(wsb + 0);            // 10000x512
  float* kk = (float*)(wsb + 20480000);    // 10000x512
  float* vv = (float*)(wsb + 40960000);    // 10000x512
  float* att = (float*)(wsb + 61440000);   // 10000x512
  float* h = (float*)(wsb + 81920000);     // 10000x128
  int* counts = (int*)(wsb + 87040000);    // 10000 (becomes cursor)
  int* row_start = (int*)(wsb + 87080000); // 10001
  int* col_src = (int*)(wsb + 87120016);   // 160000
  float* posw = (float*)(wsb + 87760016);  // 160000
  float* m1 = q;                           // reuse (10000x256)
  float* m2 = kk;                          // reuse (10000x256)

  const int* e_src = eidx;
  const int* e_dst = eidx + NE;

  // CSR build (reused by both GAT layers)
  zero_kernel<<<(NN + 255) / 256, 256, 0, stream>>>(counts, NN);
  hist_kernel<<<(NE + 255) / 256, 256, 0, stream>>>(e_dst, counts);
  scan_kernel<<<1, 1024, 0, stream>>>(counts, row_start);
  scatter_kernel<<<(NE + 255) / 256, 256, 0, stream>>>(e_src, e_dst, obs, counts, col_src, posw);

  // layer 0
  proj0_kernel<<<(NN * 512) / 256, 256, 0, stream>>>(obs, wq0, wk0, wv0, q, kk, vv);
  gat_kernel<<<NN / 4, 256, 0, stream>>>(q, kk, vv, row_start, col_src, posw, att);
  gemm64<<<dim3(157, 2), 256, 0, stream>>>(att, wo0, bo0, h, NN, 128, 512, 0);

  // layer 1 projections
  gemm64<<<dim3(157, 8), 256, 0, stream>>>(h, wq1, nullptr, q, NN, 512, 128, 0);
  gemm64<<<dim3(157, 8), 256, 0, stream>>>(h, wk1, nullptr, kk, NN, 512, 128, 0);
  gemm64<<<dim3(157, 8), 256, 0, stream>>>(h, wv1, nullptr, vv, NN, 512, 128, 0);
  gat_kernel<<<NN / 4, 256, 0, stream>>>(q, kk, vv, row_start, col_src, posw, att);
  gemm64<<<dim3(157, 2), 256, 0, stream>>>(att, wo1, bo1, h, NN, 128, 512, 0);

  // MLP
  gemm64<<<dim3(157, 4), 256, 0, stream>>>(h, w1, b1, m1, NN, 256, 128, 1);
  gemm64<<<dim3(157, 4), 256, 0, stream>>>(m1, w2, b2, m2, NN, 256, 256, 1);
  final_kernel<<<(NN + 255) / 256, 256, 0, stream>>>(m2, w3, b3, outp);
}

// Round 2
// 345.223 us; speedup vs baseline: 1.4473x; 1.4473x over previous
//
#include <hip/hip_runtime.h>
#include <math.h>

#define NN 10000
#define NE 160000
#define SCALE_F 0.17677669529663687f

typedef _Float16 f16x8 __attribute__((ext_vector_type(8)));
typedef float f32x4 __attribute__((ext_vector_type(4)));

// ---------------- CSR build ----------------
__global__ __launch_bounds__(256) void zero_kernel(int* __restrict__ p, int n) {
  int i = blockIdx.x * 256 + threadIdx.x;
  if (i < n) p[i] = 0;
}

__global__ __launch_bounds__(256) void hist_kernel(const int* __restrict__ dst, int* __restrict__ counts) {
  int e = blockIdx.x * 256 + threadIdx.x;
  if (e < NE) atomicAdd(&counts[dst[e]], 1);
}

__global__ __launch_bounds__(1024) void scan_kernel(int* __restrict__ counts, int* __restrict__ row_start) {
  __shared__ int part[1024];
  int tid = threadIdx.x;
  const int PER = 10;
  int base = tid * PER;
  int loc[PER];
  int sum = 0;
#pragma unroll
  for (int i = 0; i < PER; ++i) {
    int idx = base + i;
    int c = (idx < NN) ? counts[idx] : 0;
    loc[i] = sum;
    sum += c;
  }
  part[tid] = sum;
  __syncthreads();
  for (int off = 1; off < 1024; off <<= 1) {
    int t = (tid >= off) ? part[tid - off] : 0;
    __syncthreads();
    part[tid] += t;
    __syncthreads();
  }
  int offset = (tid > 0) ? part[tid - 1] : 0;
#pragma unroll
  for (int i = 0; i < PER; ++i) {
    int idx = base + i;
    if (idx < NN) {
      int st = offset + loc[i];
      row_start[idx] = st;
      counts[idx] = st;
    }
  }
  if (tid == 1023) row_start[NN] = part[1023];
}

__global__ __launch_bounds__(256) void scatter_kernel(const int* __restrict__ src, const int* __restrict__ dst,
                                                      const float* __restrict__ obs, int* __restrict__ cursor,
                                                      int* __restrict__ col_src, float* __restrict__ posw) {
  int e = blockIdx.x * 256 + threadIdx.x;
  if (e >= NE) return;
  int s = src[e], d = dst[e];
  int p = atomicAdd(&cursor[d], 1);
  col_src[p] = s;
  float dx = obs[d * 37 + 0] - obs[s * 37 + 0];
  float dy = obs[d * 37 + 1] - obs[s * 37 + 1];
  posw[p] = __expf(-sqrtf(dx * dx + dy * dy));
}

// ---------------- weight transpose + f16 convert: dst[n*K+k] = (f16)src[k*N+n] ----------------
__global__ __launch_bounds__(256) void convw_kernel(const float* __restrict__ wo0, const float* __restrict__ wq1,
                                                    const float* __restrict__ wk1, const float* __restrict__ wv1,
                                                    const float* __restrict__ wo1, const float* __restrict__ w1,
                                                    const float* __restrict__ w2, _Float16* __restrict__ dst) {
  int t = blockIdx.x * 256 + threadIdx.x;
  const float* s;
  _Float16* d;
  int K, N, i;
  if (t < 65536)       { s = wo0; d = dst + 0;      K = 512; N = 128; i = t; }
  else if (t < 131072) { s = wq1; d = dst + 65536;  K = 128; N = 512; i = t - 65536; }
  else if (t < 196608) { s = wk1; d = dst + 131072; K = 128; N = 512; i = t - 131072; }
  else if (t < 262144) { s = wv1; d = dst + 196608; K = 128; N = 512; i = t - 196608; }
  else if (t < 327680) { s = wo1; d = dst + 262144; K = 512; N = 128; i = t - 262144; }
  else if (t < 360448) { s = w1;  d = dst + 327680; K = 128; N = 256; i = t - 327680; }
  else if (t < 425984) { s = w2;  d = dst + 360448; K = 256; N = 256; i = t - 360448; }
  else return;
  int n = i / K, k = i % K;
  d[i] = (_Float16)s[k * N + n];
}

// ---------------- layer-0 projections (fp32 compute, f16 store) ----------------
__global__ __launch_bounds__(256) void proj0_kernel(const float* __restrict__ obs,
                                                    const float* __restrict__ wq, const float* __restrict__ wk,
                                                    const float* __restrict__ wv,
                                                    _Float16* __restrict__ q, _Float16* __restrict__ k,
                                                    _Float16* __restrict__ v) {
  int t = blockIdx.x * 256 + threadIdx.x;
  if (t >= NN * 512) return;
  int c = t & 511;
  int n = t >> 9;
  const float* orow = obs + n * 37;
  float o[37];
#pragma unroll
  for (int i = 0; i < 37; ++i) o[i] = orow[i];
  float aq = 0.f, ak = 0.f, av = 0.f;
#pragma unroll
  for (int f = 0; f < 12; ++f) aq += o[f] * wq[f * 512 + c];
#pragma unroll
  for (int f = 12; f < 19; ++f) aq += o[30 + f - 12] * wq[f * 512 + c];
#pragma unroll
  for (int f = 0; f < 12; ++f) ak += o[12 + f] * wk[f * 512 + c];
#pragma unroll
  for (int f = 12; f < 16; ++f) ak += o[26 + f - 12] * wk[f * 512 + c];
#pragma unroll
  for (int f = 0; f < 18; ++f) av += o[12 + f] * wv[f * 512 + c];
  q[t] = (_Float16)aq;
  k[t] = (_Float16)ak;
  v[t] = (_Float16)av;
}

// ---------------- fused GAT edge kernel (one wave per node, online softmax, f16 data) ----------------
__global__ __launch_bounds__(256) void gat_kernel(const _Float16* __restrict__ q, const _Float16* __restrict__ k,
                                                  const _Float16* __restrict__ v, const int* __restrict__ row_start,
                                                  const int* __restrict__ col_src, const float* __restrict__ posw,
                                                  _Float16* __restrict__ out) {
  int wave = threadIdx.x >> 6;
  int lane = threadIdx.x & 63;
  int n = blockIdx.x * 4 + wave;
  if (n >= NN) return;
  int base = n * 512 + lane * 8;
  f16x8 qv = *(const f16x8*)(q + base);
  float q0 = (float)qv[0] * SCALE_F, q1 = (float)qv[1] * SCALE_F, q2 = (float)qv[2] * SCALE_F,
        q3 = (float)qv[3] * SCALE_F, q4 = (float)qv[4] * SCALE_F, q5 = (float)qv[5] * SCALE_F,
        q6 = (float)qv[6] * SCALE_F, q7 = (float)qv[7] * SCALE_F;
  int s0 = row_start[n], s1 = row_start[n + 1];
  float m = -INFINITY, den = 0.f;
  float o0 = 0.f, o1 = 0.f, o2 = 0.f, o3 = 0.f, o4 = 0.f, o5 = 0.f, o6 = 0.f, o7 = 0.f;
  for (int j = s0; j < s1; ++j) {
    int s = col_src[j];
    float pw = posw[j];
    int sb = s * 512 + lane * 8;
    f16x8 kv = *(const f16x8*)(k + sb);
    float dot = q0 * (float)kv[0] + q1 * (float)kv[1] + q2 * (float)kv[2] + q3 * (float)kv[3] +
                q4 * (float)kv[4] + q5 * (float)kv[5] + q6 * (float)kv[6] + q7 * (float)kv[7];
    dot += __shfl_xor(dot, 1);
    dot += __shfl_xor(dot, 2);
    dot += __shfl_xor(dot, 4);
    dot += __shfl_xor(dot, 8);
    float a = dot * pw;
    float mn = fmaxf(m, a);
    float f = __expf(m - mn);
    float w = __expf(a - mn);
    den = den * f + w;
    m = mn;
    f16x8 vv8 = *(const f16x8*)(v + sb);
    o0 = o0 * f + w * (float)vv8[0];
    o1 = o1 * f + w * (float)vv8[1];
    o2 = o2 * f + w * (float)vv8[2];
    o3 = o3 * f + w * (float)vv8[3];
    o4 = o4 * f + w * (float)vv8[4];
    o5 = o5 * f + w * (float)vv8[5];
    o6 = o6 * f + w * (float)vv8[6];
    o7 = o7 * f + w * (float)vv8[7];
  }
  float inv = 1.f / (den + 1e-16f);
  f16x8 r;
  r[0] = (_Float16)(o0 * inv); r[1] = (_Float16)(o1 * inv);
  r[2] = (_Float16)(o2 * inv); r[3] = (_Float16)(o3 * inv);
  r[4] = (_Float16)(o4 * inv); r[5] = (_Float16)(o5 * inv);
  r[6] = (_Float16)(o6 * inv); r[7] = (_Float16)(o7 * inv);
  *(f16x8*)(out + base) = r;
}

// ---------------- MFMA f16 GEMM: C(MxN,f16) = A(MxK,f16) @ BT(NxK,f16)^T (+bias,+relu) ----------------
// BM=128, BN=64, BK=64; 256 threads = 4 waves (2x2), each wave 64x32 (4x2 frags of 16x16x32).
// LDS rows padded 64->72 f16 (144B) for conflict-free ds_read_b128.
template <int BIAS, int RELU>
__global__ __launch_bounds__(256) void gemm_mfma(const _Float16* __restrict__ A, const _Float16* __restrict__ BT,
                                                 const float* __restrict__ bias, _Float16* __restrict__ C,
                                                 int M, int N, int K) {
  __shared__ _Float16 As[128 * 72];
  __shared__ _Float16 Bs[64 * 72];
  int tid = threadIdx.x;
  int wave = tid >> 6, lane = tid & 63;
  int l15 = lane & 15, lq = lane >> 4;
  int wr = (wave >> 1) * 64, wc = (wave & 1) * 32;
  int m0 = blockIdx.x * 128, n0 = blockIdx.y * 64;
  f32x4 acc[4][2] = {};
  for (int k0 = 0; k0 < K; k0 += 64) {
    uint4 areg[4];
#pragma unroll
    for (int i = 0; i < 4; ++i) {
      int idx = tid + i * 256;
      int row = idx >> 3;
      int col = (idx & 7) << 3;
      int gr = m0 + row;
      if (gr > M - 1) gr = M - 1;
      areg[i] = *(const uint4*)(A + (size_t)gr * K + k0 + col);
    }
    uint4 breg[2];
#pragma unroll
    for (int i = 0; i < 2; ++i) {
      int idx = tid + i * 256;
      int col = idx >> 3;
      int kc = (idx & 7) << 3;
      breg[i] = *(const uint4*)(BT + (size_t)(n0 + col) * K + k0 + kc);
    }
    __syncthreads();
#pragma unroll
    for (int i = 0; i < 4; ++i) {
      int idx = tid + i * 256;
      int row = idx >> 3;
      int col = (idx & 7) << 3;
      *(uint4*)&As[row * 72 + col] = areg[i];
    }
#pragma unroll
    for (int i = 0; i < 2; ++i) {
      int idx = tid + i * 256;
      int col = idx >> 3;
      int kc = (idx & 7) << 3;
      *(uint4*)&Bs[col * 72 + kc] = breg[i];
    }
    __syncthreads();
#pragma unroll
    for (int ks = 0; ks < 2; ++ks) {
      int kc = ks * 32 + lq * 8;
      f16x8 a0 = *(const f16x8*)&As[(wr + 0 + l15) * 72 + kc];
      f16x8 a1 = *(const f16x8*)&As[(wr + 16 + l15) * 72 + kc];
      f16x8 a2 = *(const f16x8*)&As[(wr + 32 + l15) * 72 + kc];
      f16x8 a3 = *(const f16x8*)&As[(wr + 48 + l15) * 72 + kc];
      f16x8 b0 = *(const f16x8*)&Bs[(wc + 0 + l15) * 72 + kc];
      f16x8 b1 = *(const f16x8*)&Bs[(wc + 16 + l15) * 72 + kc];
      acc[0][0] = __builtin_amdgcn_mfma_f32_16x16x32_f16(a0, b0, acc[0][0], 0, 0, 0);
      acc[0][1] = __builtin_amdgcn_mfma_f32_16x16x32_f16(a0, b1, acc[0][1], 0, 0, 0);
      acc[1][0] = __builtin_amdgcn_mfma_f32_16x16x32_f16(a1, b0, acc[1][0], 0, 0, 0);
      acc[1][1] = __builtin_amdgcn_mfma_f32_16x16x32_f16(a1, b1, acc[1][1], 0, 0, 0);
      acc[2][0] = __builtin_amdgcn_mfma_f32_16x16x32_f16(a2, b0, acc[2][0], 0, 0, 0);
      acc[2][1] = __builtin_amdgcn_mfma_f32_16x16x32_f16(a2, b1, acc[2][1], 0, 0, 0);
      acc[3][0] = __builtin_amdgcn_mfma_f32_16x16x32_f16(a3, b0, acc[3][0], 0, 0, 0);
      acc[3][1] = __builtin_amdgcn_mfma_f32_16x16x32_f16(a3, b1, acc[3][1], 0, 0, 0);
    }
    __syncthreads();
  }
#pragma unroll
  for (int ri = 0; ri < 4; ++ri) {
    int gr0 = m0 + wr + ri * 16 + lq * 4;
#pragma unroll
    for (int ci = 0; ci < 2; ++ci) {
      int gc = n0 + wc + ci * 16 + l15;
      float bb = 0.f;
      if (BIAS) bb = bias[gc];
#pragma unroll
      for (int j = 0; j < 4; ++j) {
        int gr = gr0 + j;
        if (gr < M) {
          float x = acc[ri][ci][j] + bb;
          if (RELU) x = fmaxf(x, 0.f);
          C[(size_t)gr * N + gc] = (_Float16)x;
        }
      }
    }
  }
}

// ---------------- final tiny GEMM: (10000x256 f16) @ (256x2 f32) + b ----------------
__global__ __launch_bounds__(256) void final_kernel(const _Float16* __restrict__ X, const float* __restrict__ w3,
                                                    const float* __restrict__ b3, float* __restrict__ out) {
  int n = blockIdx.x * 256 + threadIdx.x;
  if (n >= NN) return;
  float a0 = b3[0], a1 = b3[1];
  const f16x8* xr = (const f16x8*)(X + n * 256);
  for (int j = 0; j < 32; ++j) {
    f16x8 xv = xr[j];
#pragma unroll
    for (int e = 0; e < 8; ++e) {
      float x = (float)xv[e];
      int c = j * 8 + e;
      a0 += x * w3[c * 2 + 0];
      a1 += x * w3[c * 2 + 1];
    }
  }
  out[n * 2 + 0] = a0;
  out[n * 2 + 1] = a1;
}

extern "C" void kernel_launch(void* const* d_in, const int* in_sizes, int n_in,
                              void* d_out, int out_size, void* d_ws, size_t ws_size,
                              hipStream_t stream) {
  const float* obs = (const float*)d_in[0];
  const int* eidx = (const int*)d_in[1];
  const float* wq0 = (const float*)d_in[2];
  const float* wk0 = (const float*)d_in[3];
  const float* wv0 = (const float*)d_in[4];
  const float* wo0 = (const float*)d_in[5];
  const float* bo0 = (const float*)d_in[6];
  const float* wq1 = (const float*)d_in[7];
  const float* wk1 = (const float*)d_in[8];
  const float* wv1 = (const float*)d_in[9];
  const float* wo1 = (const float*)d_in[10];
  const float* bo1 = (const float*)d_in[11];
  const float* w1 = (const float*)d_in[12];
  const float* b1 = (const float*)d_in[13];
  const float* w2 = (const float*)d_in[14];
  const float* b2 = (const float*)d_in[15];
  const float* w3 = (const float*)d_in[16];
  const float* b3 = (const float*)d_in[17];
  float* outp = (float*)d_out;

  char* wsb = (char*)d_ws;
  _Float16* q = (_Float16*)(wsb + 0);           // 10000x512
  _Float16* kk = (_Float16*)(wsb + 10240000);   // 10000x512
  _Float16* vv = (_Float16*)(wsb + 20480000);   // 10000x512
  _Float16* att = (_Float16*)(wsb + 30720000);  // 10000x512
  _Float16* h = (_Float16*)(wsb + 40960000);    // 10000x128
  _Float16* wT = (_Float16*)(wsb + 43520000);   // 425984 f16
  int* counts = (int*)(wsb + 44371968);         // 10000
  int* row_start = (int*)(wsb + 44411968);      // 10001
  int* col_src = (int*)(wsb + 44451972);        // 160000
  float* posw = (float*)(wsb + 45091972);       // 160000
  _Float16* m1 = q;                             // reuse (10000x256)
  _Float16* m2 = kk;                            // reuse (10000x256)

  _Float16* wo0T = wT + 0;
  _Float16* wq1T = wT + 65536;
  _Float16* wk1T = wT + 131072;
  _Float16* wv1T = wT + 196608;
  _Float16* wo1T = wT + 262144;
  _Float16* w1T = wT + 327680;
  _Float16* w2T = wT + 360448;

  const int* e_src = eidx;
  const int* e_dst = eidx + NE;

  // CSR build + weight conversion
  zero_kernel<<<(NN + 255) / 256, 256, 0, stream>>>(counts, NN);
  hist_kernel<<<(NE + 255) / 256, 256, 0, stream>>>(e_dst, counts);
  convw_kernel<<<1664, 256, 0, stream>>>(wo0, wq1, wk1, wv1, wo1, w1, w2, wT);
  scan_kernel<<<1, 1024, 0, stream>>>(counts, row_start);
  scatter_kernel<<<(NE + 255) / 256, 256, 0, stream>>>(e_src, e_dst, obs, counts, col_src, posw);

  // layer 0
  proj0_kernel<<<(NN * 512) / 256, 256, 0, stream>>>(obs, wq0, wk0, wv0, q, kk, vv);
  gat_kernel<<<NN / 4, 256, 0, stream>>>(q, kk, vv, row_start, col_src, posw, att);
  gemm_mfma<1, 0><<<dim3(79, 2), 256, 0, stream>>>(att, wo0T, bo0, h, NN, 128, 512);

  // layer 1
  gemm_mfma<0, 0><<<dim3(79, 8), 256, 0, stream>>>(h, wq1T, nullptr, q, NN, 512, 128);
  gemm_mfma<0, 0><<<dim3(79, 8), 256, 0, stream>>>(h, wk1T, nullptr, kk, NN, 512, 128);
  gemm_mfma<0, 0><<<dim3(79, 8), 256, 0, stream>>>(h, wv1T, nullptr, vv, NN, 512, 128);
  gat_kernel<<<NN / 4, 256, 0, stream>>>(q, kk, vv, row_start, col_src, posw, att);
  gemm_mfma<1, 0><<<dim3(79, 2), 256, 0, stream>>>(att, wo1T, bo1, h, NN, 128, 512);

  // MLP
  gemm_mfma<1, 1><<<dim3(79, 4), 256, 0, stream>>>(h, w1T, b1, m1, NN, 256, 128);
  gemm_mfma<1, 1><<<dim3(79, 4), 256, 0, stream>>>(m1, w2T, b2, m2, NN, 256, 256);
  final_kernel<<<(NN + 255) / 256, 256, 0, stream>>>(m2, w3, b3, outp);
}

// Round 3
// 292.467 us; speedup vs baseline: 1.7083x; 1.1804x over previous
//
#include <hip/hip_runtime.h>
#include <math.h>

#define NN 10000
#define NE 160000
#define SCALE_F 0.17677669529663687f

typedef _Float16 f16x8 __attribute__((ext_vector_type(8)));
typedef float f32x4 __attribute__((ext_vector_type(4)));

// ---------------- CSR build ----------------
__global__ __launch_bounds__(256) void zero_kernel(int* __restrict__ p, int n) {
  int i = blockIdx.x * 256 + threadIdx.x;
  if (i < n) p[i] = 0;
}

__global__ __launch_bounds__(256) void hist_kernel(const int* __restrict__ dst, int* __restrict__ counts) {
  int e = blockIdx.x * 256 + threadIdx.x;
  if (e < NE) atomicAdd(&counts[dst[e]], 1);
}

__global__ __launch_bounds__(1024) void scan_kernel(int* __restrict__ counts, int* __restrict__ row_start) {
  __shared__ int part[1024];
  int tid = threadIdx.x;
  const int PER = 10;
  int base = tid * PER;
  int loc[PER];
  int sum = 0;
#pragma unroll
  for (int i = 0; i < PER; ++i) {
    int idx = base + i;
    int c = (idx < NN) ? counts[idx] : 0;
    loc[i] = sum;
    sum += c;
  }
  part[tid] = sum;
  __syncthreads();
  for (int off = 1; off < 1024; off <<= 1) {
    int t = (tid >= off) ? part[tid - off] : 0;
    __syncthreads();
    part[tid] += t;
    __syncthreads();
  }
  int offset = (tid > 0) ? part[tid - 1] : 0;
#pragma unroll
  for (int i = 0; i < PER; ++i) {
    int idx = base + i;
    if (idx < NN) {
      int st = offset + loc[i];
      row_start[idx] = st;
      counts[idx] = st;
    }
  }
  if (tid == 1023) row_start[NN] = part[1023];
}

__global__ __launch_bounds__(256) void scatter_kernel(const int* __restrict__ src, const int* __restrict__ dst,
                                                      const float* __restrict__ obs, int* __restrict__ cursor,
                                                      int* __restrict__ col_src, float* __restrict__ posw) {
  int e = blockIdx.x * 256 + threadIdx.x;
  if (e >= NE) return;
  int s = src[e], d = dst[e];
  int p = atomicAdd(&cursor[d], 1);
  col_src[p] = s;
  float dx = obs[d * 37 + 0] - obs[s * 37 + 0];
  float dy = obs[d * 37 + 1] - obs[s * 37 + 1];
  posw[p] = __expf(-sqrtf(dx * dx + dy * dy));
}

// ---------------- feature pack: A0[n][64] = [qf(19) | kf(16) | vf(18) | 0pad] ----------------
__global__ __launch_bounds__(256) void pack_kernel(const float* __restrict__ obs, _Float16* __restrict__ A0) {
  int t = blockIdx.x * 256 + threadIdx.x;
  if (t >= NN * 64) return;
  int n = t >> 6, k = t & 63;
  const float* o = obs + n * 37;
  float x = 0.f;
  if (k < 12) x = o[k];
  else if (k < 19) x = o[30 + k - 12];
  else if (k < 31) x = o[12 + k - 19];
  else if (k < 35) x = o[26 + k - 31];
  else if (k < 53) x = o[12 + k - 35];
  A0[t] = (_Float16)x;
}

// ---------------- weight transpose + f16 convert ----------------
// w0T   [1536][64]  block-diag from wq0(19x512), wk0(16x512), wv0(18x512)
// wqkv1T[1536][128] from wq1/wk1/wv1 (128x512 each)
// wo0T  [128][512], wo1T [128][512], w1T [256][128], w2T [256][256]
__global__ __launch_bounds__(256) void convw_kernel(const float* __restrict__ wq0, const float* __restrict__ wk0,
                                                    const float* __restrict__ wv0,
                                                    const float* __restrict__ wo0, const float* __restrict__ wq1,
                                                    const float* __restrict__ wk1, const float* __restrict__ wv1,
                                                    const float* __restrict__ wo1, const float* __restrict__ w1,
                                                    const float* __restrict__ w2, _Float16* __restrict__ dst) {
  int t = blockIdx.x * 256 + threadIdx.x;
  if (t < 98304) { // w0T
    int c = t >> 6, k = t & 63;
    float x = 0.f;
    if (c < 512) { if (k < 19) x = wq0[k * 512 + c]; }
    else if (c < 1024) { if (k >= 19 && k < 35) x = wk0[(k - 19) * 512 + (c - 512)]; }
    else { if (k >= 35 && k < 53) x = wv0[(k - 35) * 512 + (c - 1024)]; }
    dst[t] = (_Float16)x;
    return;
  }
  int t1 = t - 98304;
  if (t1 < 196608) { // wqkv1T
    int c = t1 >> 7, k = t1 & 127;
    float x;
    if (c < 512) x = wq1[k * 512 + c];
    else if (c < 1024) x = wk1[k * 512 + (c - 512)];
    else x = wv1[k * 512 + (c - 1024)];
    dst[98304 + t1] = (_Float16)x;
    return;
  }
  int t2 = t1 - 196608;
  if (t2 < 65536) { // wo0T [128][512]
    int n = t2 >> 9, k = t2 & 511;
    dst[294912 + t2] = (_Float16)wo0[k * 128 + n];
    return;
  }
  int t3 = t2 - 65536;
  if (t3 < 65536) { // wo1T
    int n = t3 >> 9, k = t3 & 511;
    dst[360448 + t3] = (_Float16)wo1[k * 128 + n];
    return;
  }
  int t4 = t3 - 65536;
  if (t4 < 32768) { // w1T [256][128]
    int n = t4 >> 7, k = t4 & 127;
    dst[425984 + t4] = (_Float16)w1[k * 256 + n];
    return;
  }
  int t5 = t4 - 32768;
  if (t5 < 65536) { // w2T [256][256]
    int n = t5 >> 8, k = t5 & 255;
    dst[458752 + t5] = (_Float16)w2[k * 256 + n];
  }
}

// ---------------- fused GAT edge kernel (one wave/node, online softmax, 2x unroll) ----------------
// qkv layout: per node 1536 f16 = [q(512) | k(512) | v(512)]
__global__ __launch_bounds__(256) void gat_kernel(const _Float16* __restrict__ qkv, const int* __restrict__ row_start,
                                                  const int* __restrict__ col_src, const float* __restrict__ posw,
                                                  _Float16* __restrict__ out) {
  int wave = threadIdx.x >> 6;
  int lane = threadIdx.x & 63;
  int n = blockIdx.x * 4 + wave;
  if (n >= NN) return;
  f16x8 qv = *(const f16x8*)(qkv + n * 1536 + lane * 8);
  float q0 = (float)qv[0] * SCALE_F, q1 = (float)qv[1] * SCALE_F, q2 = (float)qv[2] * SCALE_F,
        q3 = (float)qv[3] * SCALE_F, q4 = (float)qv[4] * SCALE_F, q5 = (float)qv[5] * SCALE_F,
        q6 = (float)qv[6] * SCALE_F, q7 = (float)qv[7] * SCALE_F;
  int s0 = row_start[n], s1 = row_start[n + 1];
  float m = -INFINITY, den = 0.f;
  float o0 = 0.f, o1 = 0.f, o2 = 0.f, o3 = 0.f, o4 = 0.f, o5 = 0.f, o6 = 0.f, o7 = 0.f;
  int j = s0;
  for (; j + 1 < s1; j += 2) {
    int sA = col_src[j], sB = col_src[j + 1];
    float pwA = posw[j], pwB = posw[j + 1];
    const _Float16* pA = qkv + sA * 1536 + 512 + lane * 8;
    const _Float16* pB = qkv + sB * 1536 + 512 + lane * 8;
    f16x8 kA = *(const f16x8*)pA;
    f16x8 kB = *(const f16x8*)pB;
    f16x8 vA = *(const f16x8*)(pA + 512);
    f16x8 vB = *(const f16x8*)(pB + 512);
    float dA = q0 * (float)kA[0] + q1 * (float)kA[1] + q2 * (float)kA[2] + q3 * (float)kA[3] +
               q4 * (float)kA[4] + q5 * (float)kA[5] + q6 * (float)kA[6] + q7 * (float)kA[7];
    float dB = q0 * (float)kB[0] + q1 * (float)kB[1] + q2 * (float)kB[2] + q3 * (float)kB[3] +
               q4 * (float)kB[4] + q5 * (float)kB[5] + q6 * (float)kB[6] + q7 * (float)kB[7];
    dA += __shfl_xor(dA, 1); dB += __shfl_xor(dB, 1);
    dA += __shfl_xor(dA, 2); dB += __shfl_xor(dB, 2);
    dA += __shfl_xor(dA, 4); dB += __shfl_xor(dB, 4);
    dA += __shfl_xor(dA, 8); dB += __shfl_xor(dB, 8);
    float aA = dA * pwA, aB = dB * pwB;
    float mn = fmaxf(m, fmaxf(aA, aB));
    float f = __expf(m - mn);
    float wA = __expf(aA - mn), wB = __expf(aB - mn);
    den = den * f + wA + wB;
    m = mn;
    o0 = o0 * f + wA * (float)vA[0] + wB * (float)vB[0];
    o1 = o1 * f + wA * (float)vA[1] + wB * (float)vB[1];
    o2 = o2 * f + wA * (float)vA[2] + wB * (float)vB[2];
    o3 = o3 * f + wA * (float)vA[3] + wB * (float)vB[3];
    o4 = o4 * f + wA * (float)vA[4] + wB * (float)vB[4];
    o5 = o5 * f + wA * (float)vA[5] + wB * (float)vB[5];
    o6 = o6 * f + wA * (float)vA[6] + wB * (float)vB[6];
    o7 = o7 * f + wA * (float)vA[7] + wB * (float)vB[7];
  }
  if (j < s1) {
    int s = col_src[j];
    float pw = posw[j];
    const _Float16* p = qkv + s * 1536 + 512 + lane * 8;
    f16x8 kv = *(const f16x8*)p;
    f16x8 vv8 = *(const f16x8*)(p + 512);
    float dot = q0 * (float)kv[0] + q1 * (float)kv[1] + q2 * (float)kv[2] + q3 * (float)kv[3] +
                q4 * (float)kv[4] + q5 * (float)kv[5] + q6 * (float)kv[6] + q7 * (float)kv[7];
    dot += __shfl_xor(dot, 1);
    dot += __shfl_xor(dot, 2);
    dot += __shfl_xor(dot, 4);
    dot += __shfl_xor(dot, 8);
    float a = dot * pw;
    float mn = fmaxf(m, a);
    float f = __expf(m - mn);
    float w = __expf(a - mn);
    den = den * f + w;
    o0 = o0 * f + w * (float)vv8[0];
    o1 = o1 * f + w * (float)vv8[1];
    o2 = o2 * f + w * (float)vv8[2];
    o3 = o3 * f + w * (float)vv8[3];
    o4 = o4 * f + w * (float)vv8[4];
    o5 = o5 * f + w * (float)vv8[5];
    o6 = o6 * f + w * (float)vv8[6];
    o7 = o7 * f + w * (float)vv8[7];
  }
  float inv = 1.f / (den + 1e-16f);
  f16x8 r;
  r[0] = (_Float16)(o0 * inv); r[1] = (_Float16)(o1 * inv);
  r[2] = (_Float16)(o2 * inv); r[3] = (_Float16)(o3 * inv);
  r[4] = (_Float16)(o4 * inv); r[5] = (_Float16)(o5 * inv);
  r[6] = (_Float16)(o6 * inv); r[7] = (_Float16)(o7 * inv);
  *(f16x8*)(out + n * 512 + lane * 8) = r;
}

// ---------------- MFMA f16 GEMM: C(MxN,f16) = A(MxK,f16) @ BT(NxK,f16)^T (+bias,+relu) ----------------
// BM=128, BN=64, BK=64; 256 threads = 4 waves (2x2), each wave 64x32 (4x2 frags of 16x16x32).
template <int BIAS, int RELU>
__global__ __launch_bounds__(256) void gemm_mfma(const _Float16* __restrict__ A, const _Float16* __restrict__ BT,
                                                 const float* __restrict__ bias, _Float16* __restrict__ C,
                                                 int M, int N, int K) {
  __shared__ _Float16 As[128 * 72];
  __shared__ _Float16 Bs[64 * 72];
  int tid = threadIdx.x;
  int wave = tid >> 6, lane = tid & 63;
  int l15 = lane & 15, lq = lane >> 4;
  int wr = (wave >> 1) * 64, wc = (wave & 1) * 32;
  int m0 = blockIdx.x * 128, n0 = blockIdx.y * 64;
  f32x4 acc[4][2] = {};
  for (int k0 = 0; k0 < K; k0 += 64) {
    uint4 areg[4];
#pragma unroll
    for (int i = 0; i < 4; ++i) {
      int idx = tid + i * 256;
      int row = idx >> 3;
      int col = (idx & 7) << 3;
      int gr = m0 + row;
      if (gr > M - 1) gr = M - 1;
      areg[i] = *(const uint4*)(A + (size_t)gr * K + k0 + col);
    }
    uint4 breg[2];
#pragma unroll
    for (int i = 0; i < 2; ++i) {
      int idx = tid + i * 256;
      int col = idx >> 3;
      int kc = (idx & 7) << 3;
      breg[i] = *(const uint4*)(BT + (size_t)(n0 + col) * K + k0 + kc);
    }
    __syncthreads();
#pragma unroll
    for (int i = 0; i < 4; ++i) {
      int idx = tid + i * 256;
      int row = idx >> 3;
      int col = (idx & 7) << 3;
      *(uint4*)&As[row * 72 + col] = areg[i];
    }
#pragma unroll
    for (int i = 0; i < 2; ++i) {
      int idx = tid + i * 256;
      int col = idx >> 3;
      int kc = (idx & 7) << 3;
      *(uint4*)&Bs[col * 72 + kc] = breg[i];
    }
    __syncthreads();
#pragma unroll
    for (int ks = 0; ks < 2; ++ks) {
      int kc = ks * 32 + lq * 8;
      f16x8 a0 = *(const f16x8*)&As[(wr + 0 + l15) * 72 + kc];
      f16x8 a1 = *(const f16x8*)&As[(wr + 16 + l15) * 72 + kc];
      f16x8 a2 = *(const f16x8*)&As[(wr + 32 + l15) * 72 + kc];
      f16x8 a3 = *(const f16x8*)&As[(wr + 48 + l15) * 72 + kc];
      f16x8 b0 = *(const f16x8*)&Bs[(wc + 0 + l15) * 72 + kc];
      f16x8 b1 = *(const f16x8*)&Bs[(wc + 16 + l15) * 72 + kc];
      acc[0][0] = __builtin_amdgcn_mfma_f32_16x16x32_f16(a0, b0, acc[0][0], 0, 0, 0);
      acc[0][1] = __builtin_amdgcn_mfma_f32_16x16x32_f16(a0, b1, acc[0][1], 0, 0, 0);
      acc[1][0] = __builtin_amdgcn_mfma_f32_16x16x32_f16(a1, b0, acc[1][0], 0, 0, 0);
      acc[1][1] = __builtin_amdgcn_mfma_f32_16x16x32_f16(a1, b1, acc[1][1], 0, 0, 0);
      acc[2][0] = __builtin_amdgcn_mfma_f32_16x16x32_f16(a2, b0, acc[2][0], 0, 0, 0);
      acc[2][1] = __builtin_amdgcn_mfma_f32_16x16x32_f16(a2, b1, acc[2][1], 0, 0, 0);
      acc[3][0] = __builtin_amdgcn_mfma_f32_16x16x32_f16(a3, b0, acc[3][0], 0, 0, 0);
      acc[3][1] = __builtin_amdgcn_mfma_f32_16x16x32_f16(a3, b1, acc[3][1], 0, 0, 0);
    }
    __syncthreads();
  }
#pragma unroll
  for (int ri = 0; ri < 4; ++ri) {
    int gr0 = m0 + wr + ri * 16 + lq * 4;
#pragma unroll
    for (int ci = 0; ci < 2; ++ci) {
      int gc = n0 + wc + ci * 16 + l15;
      float bb = 0.f;
      if (BIAS) bb = bias[gc];
#pragma unroll
      for (int j = 0; j < 4; ++j) {
        int gr = gr0 + j;
        if (gr < M) {
          float x = acc[ri][ci][j] + bb;
          if (RELU) x = fmaxf(x, 0.f);
          C[(size_t)gr * N + gc] = (_Float16)x;
        }
      }
    }
  }
}

// ---------------- final tiny GEMM: (10000x256 f16) @ (256x2 f32) + b ----------------
__global__ __launch_bounds__(256) void final_kernel(const _Float16* __restrict__ X, const float* __restrict__ w3,
                                                    const float* __restrict__ b3, float* __restrict__ out) {
  int n = blockIdx.x * 256 + threadIdx.x;
  if (n >= NN) return;
  float a0 = b3[0], a1 = b3[1];
  const f16x8* xr = (const f16x8*)(X + n * 256);
  for (int j = 0; j < 32; ++j) {
    f16x8 xv = xr[j];
#pragma unroll
    for (int e = 0; e < 8; ++e) {
      float x = (float)xv[e];
      int c = j * 8 + e;
      a0 += x * w3[c * 2 + 0];
      a1 += x * w3[c * 2 + 1];
    }
  }
  out[n * 2 + 0] = a0;
  out[n * 2 + 1] = a1;
}

extern "C" void kernel_launch(void* const* d_in, const int* in_sizes, int n_in,
                              void* d_out, int out_size, void* d_ws, size_t ws_size,
                              hipStream_t stream) {
  const float* obs = (const float*)d_in[0];
  const int* eidx = (const int*)d_in[1];
  const float* wq0 = (const float*)d_in[2];
  const float* wk0 = (const float*)d_in[3];
  const float* wv0 = (const float*)d_in[4];
  const float* wo0 = (const float*)d_in[5];
  const float* bo0 = (const float*)d_in[6];
  const float* wq1 = (const float*)d_in[7];
  const float* wk1 = (const float*)d_in[8];
  const float* wv1 = (const float*)d_in[9];
  const float* wo1 = (const float*)d_in[10];
  const float* bo1 = (const float*)d_in[11];
  const float* w1 = (const float*)d_in[12];
  const float* b1 = (const float*)d_in[13];
  const float* w2 = (const float*)d_in[14];
  const float* b2 = (const float*)d_in[15];
  const float* w3 = (const float*)d_in[16];
  const float* b3 = (const float*)d_in[17];
  float* outp = (float*)d_out;

  char* wsb = (char*)d_ws;
  _Float16* qkv = (_Float16*)(wsb + 0);          // 10000x1536
  _Float16* att = (_Float16*)(wsb + 30720000);   // 10000x512
  _Float16* h = (_Float16*)(wsb + 40960000);     // 10000x128
  _Float16* A0 = (_Float16*)(wsb + 43520000);    // 10000x64
  _Float16* wT = (_Float16*)(wsb + 44800000);    // 524288 f16
  int* counts = (int*)(wsb + 45848576);          // 10000
  int* row_start = (int*)(wsb + 45888576);       // 10001
  int* col_src = (int*)(wsb + 45928580);         // 160000
  float* posw = (float*)(wsb + 46568580);        // 160000
  _Float16* m1 = att;                            // reuse (10000x256)
  _Float16* m2 = qkv;                            // reuse (10000x256)

  _Float16* w0T = wT + 0;        // [1536][64]
  _Float16* wqkv1T = wT + 98304; // [1536][128]
  _Float16* wo0T = wT + 294912;  // [128][512]
  _Float16* wo1T = wT + 360448;  // [128][512]
  _Float16* w1T = wT + 425984;   // [256][128]
  _Float16* w2T = wT + 458752;   // [256][256]

  const int* e_src = eidx;
  const int* e_dst = eidx + NE;

  // CSR build + weight conversion + feature pack
  zero_kernel<<<(NN + 255) / 256, 256, 0, stream>>>(counts, NN);
  hist_kernel<<<(NE + 255) / 256, 256, 0, stream>>>(e_dst, counts);
  convw_kernel<<<2048, 256, 0, stream>>>(wq0, wk0, wv0, wo0, wq1, wk1, wv1, wo1, w1, w2, wT);
  pack_kernel<<<(NN * 64 + 255) / 256, 256, 0, stream>>>(obs, A0);
  scan_kernel<<<1, 1024, 0, stream>>>(counts, row_start);
  scatter_kernel<<<(NE + 255) / 256, 256, 0, stream>>>(e_src, e_dst, obs, counts, col_src, posw);

  // layer 0: qkv = A0 @ W0 (block-diag), then GAT, then out-proj
  gemm_mfma<0, 0><<<dim3(79, 24), 256, 0, stream>>>(A0, w0T, nullptr, qkv, NN, 1536, 64);
  gat_kernel<<<NN / 4, 256, 0, stream>>>(qkv, row_start, col_src, posw, att);
  gemm_mfma<1, 0><<<dim3(79, 2), 256, 0, stream>>>(att, wo0T, bo0, h, NN, 128, 512);

  // layer 1: fused qkv GEMM, GAT, out-proj
  gemm_mfma<0, 0><<<dim3(79, 24), 256, 0, stream>>>(h, wqkv1T, nullptr, qkv, NN, 1536, 128);
  gat_kernel<<<NN / 4, 256, 0, stream>>>(qkv, row_start, col_src, posw, att);
  gemm_mfma<1, 0><<<dim3(79, 2), 256, 0, stream>>>(att, wo1T, bo1, h, NN, 128, 512);

  // MLP
  gemm_mfma<1, 1><<<dim3(79, 4), 256, 0, stream>>>(h, w1T, b1, m1, NN, 256, 128);
  gemm_mfma<1, 1><<<dim3(79, 4), 256, 0, stream>>>(m1, w2T, b2, m2, NN, 256, 256);
  final_kernel<<<(NN + 255) / 256, 256, 0, stream>>>(m2, w3, b3, outp);
}

// Round 5
// 213.861 us; speedup vs baseline: 2.3362x; 1.3676x over previous
//
#include <hip/hip_runtime.h>
#include <math.h>

#define NN 10000
#define NE 160000
#define SCALE_F 0.17677669529663687f

typedef _Float16 f16x8 __attribute__((ext_vector_type(8)));
typedef float f32x4 __attribute__((ext_vector_type(4)));

#if defined(__has_builtin)
#if __has_builtin(__builtin_amdgcn_global_load_lds)
#define HAS_GLL 1
#endif
#endif

// ---------------- CSR build ----------------
__global__ __launch_bounds__(256) void zero_kernel(int* __restrict__ p, int n) {
  int i = blockIdx.x * 256 + threadIdx.x;
  if (i < n) p[i] = 0;
}

__global__ __launch_bounds__(256) void hist_kernel(const int* __restrict__ dst, int* __restrict__ counts) {
  int e = blockIdx.x * 256 + threadIdx.x;
  if (e < NE) atomicAdd(&counts[dst[e]], 1);
}

__global__ __launch_bounds__(1024) void scan_kernel(int* __restrict__ counts, int* __restrict__ row_start) {
  __shared__ int part[1024];
  int tid = threadIdx.x;
  const int PER = 10;
  int base = tid * PER;
  int loc[PER];
  int sum = 0;
#pragma unroll
  for (int i = 0; i < PER; ++i) {
    int idx = base + i;
    int c = (idx < NN) ? counts[idx] : 0;
    loc[i] = sum;
    sum += c;
  }
  part[tid] = sum;
  __syncthreads();
  for (int off = 1; off < 1024; off <<= 1) {
    int t = (tid >= off) ? part[tid - off] : 0;
    __syncthreads();
    part[tid] += t;
    __syncthreads();
  }
  int offset = (tid > 0) ? part[tid - 1] : 0;
#pragma unroll
  for (int i = 0; i < PER; ++i) {
    int idx = base + i;
    if (idx < NN) {
      int st = offset + loc[i];
      row_start[idx] = st;
      counts[idx] = st;
    }
  }
  if (tid == 1023) row_start[NN] = part[1023];
}

__global__ __launch_bounds__(256) void scatter_kernel(const int* __restrict__ src, const int* __restrict__ dst,
                                                      const float* __restrict__ obs, int* __restrict__ cursor,
                                                      int* __restrict__ col_src, float* __restrict__ posw) {
  int e = blockIdx.x * 256 + threadIdx.x;
  if (e >= NE) return;
  int s = src[e], d = dst[e];
  int p = atomicAdd(&cursor[d], 1);
  col_src[p] = s;
  float dx = obs[d * 37 + 0] - obs[s * 37 + 0];
  float dy = obs[d * 37 + 1] - obs[s * 37 + 1];
  posw[p] = __expf(-sqrtf(dx * dx + dy * dy));
}

// ---------------- fused prep: weight transpose/convert + feature pack ----------------
__global__ __launch_bounds__(256) void prep_kernel(const float* __restrict__ wq0, const float* __restrict__ wk0,
                                                   const float* __restrict__ wv0,
                                                   const float* __restrict__ wo0, const float* __restrict__ wq1,
                                                   const float* __restrict__ wk1, const float* __restrict__ wv1,
                                                   const float* __restrict__ wo1, const float* __restrict__ w1,
                                                   const float* __restrict__ w2, _Float16* __restrict__ dst,
                                                   const float* __restrict__ obs, _Float16* __restrict__ A0) {
  int t = blockIdx.x * 256 + threadIdx.x;
  if (t >= 524288) { // pack part
    int tp = t - 524288;
    if (tp >= NN * 64) return;
    int n = tp >> 6, k = tp & 63;
    const float* o = obs + n * 37;
    float x = 0.f;
    if (k < 12) x = o[k];
    else if (k < 19) x = o[30 + k - 12];
    else if (k < 31) x = o[12 + k - 19];
    else if (k < 35) x = o[26 + k - 31];
    else if (k < 53) x = o[12 + k - 35];
    A0[tp] = (_Float16)x;
    return;
  }
  if (t < 98304) { // w0T block-diag [1536][64]
    int c = t >> 6, k = t & 63;
    float x = 0.f;
    if (c < 512) { if (k < 19) x = wq0[k * 512 + c]; }
    else if (c < 1024) { if (k >= 19 && k < 35) x = wk0[(k - 19) * 512 + (c - 512)]; }
    else { if (k >= 35 && k < 53) x = wv0[(k - 35) * 512 + (c - 1024)]; }
    dst[t] = (_Float16)x;
    return;
  }
  int t1 = t - 98304;
  if (t1 < 196608) { // wqkv1T [1536][128]
    int c = t1 >> 7, k = t1 & 127;
    float x;
    if (c < 512) x = wq1[k * 512 + c];
    else if (c < 1024) x = wk1[k * 512 + (c - 512)];
    else x = wv1[k * 512 + (c - 1024)];
    dst[98304 + t1] = (_Float16)x;
    return;
  }
  int t2 = t1 - 196608;
  if (t2 < 65536) { int n = t2 >> 9, k = t2 & 511; dst[294912 + t2] = (_Float16)wo0[k * 128 + n]; return; }
  int t3 = t2 - 65536;
  if (t3 < 65536) { int n = t3 >> 9, k = t3 & 511; dst[360448 + t3] = (_Float16)wo1[k * 128 + n]; return; }
  int t4 = t3 - 65536;
  if (t4 < 32768) { int n = t4 >> 7, k = t4 & 127; dst[425984 + t4] = (_Float16)w1[k * 256 + n]; return; }
  int t5 = t4 - 32768;
  if (t5 < 65536) { int n = t5 >> 8, k = t5 & 255; dst[458752 + t5] = (_Float16)w2[k * 256 + n]; }
}

// ---------------- fused GAT edge kernel: 2 waves per node, online softmax + per-HEAD LDS flash-merge ----------------
// qkv layout: per node 1536 f16 = [q(512) | k(512) | v(512)]
// NOTE: m/den are PER-HEAD (uniform within each 16-lane group after the 4-step shfl_xor reduce);
// the merge must exchange 4 (m,den) pairs per wave, indexed by lane>>4.
__global__ __launch_bounds__(256) void gat_kernel(const _Float16* __restrict__ qkv, const int* __restrict__ row_start,
                                                  const int* __restrict__ col_src, const float* __restrict__ posw,
                                                  _Float16* __restrict__ out) {
  __shared__ float sO[2][512];
  __shared__ float sMD[2][4][2];
  int tid = threadIdx.x;
  int wave = tid >> 6, lane = tid & 63;
  int ln = wave >> 1, half = wave & 1;
  int head = lane >> 4;
  int n = blockIdx.x * 2 + ln; // grid = NN/2 exactly
  f16x8 qv = *(const f16x8*)(qkv + (size_t)n * 1536 + lane * 8);
  float q0 = (float)qv[0] * SCALE_F, q1 = (float)qv[1] * SCALE_F, q2 = (float)qv[2] * SCALE_F,
        q3 = (float)qv[3] * SCALE_F, q4 = (float)qv[4] * SCALE_F, q5 = (float)qv[5] * SCALE_F,
        q6 = (float)qv[6] * SCALE_F, q7 = (float)qv[7] * SCALE_F;
  int s0 = row_start[n], s1 = row_start[n + 1];
  int mid = (s0 + s1 + 1) >> 1;
  int jb = half ? mid : s0;
  int je = half ? s1 : mid;
  float m = -INFINITY, den = 0.f;
  float o0 = 0.f, o1 = 0.f, o2 = 0.f, o3 = 0.f, o4 = 0.f, o5 = 0.f, o6 = 0.f, o7 = 0.f;
  int j = jb;
  for (; j + 1 < je; j += 2) {
    int sA = col_src[j], sB = col_src[j + 1];
    float pwA = posw[j], pwB = posw[j + 1];
    const _Float16* pA = qkv + (size_t)sA * 1536 + 512 + lane * 8;
    const _Float16* pB = qkv + (size_t)sB * 1536 + 512 + lane * 8;
    f16x8 kA = *(const f16x8*)pA;
    f16x8 kB = *(const f16x8*)pB;
    f16x8 vA = *(const f16x8*)(pA + 512);
    f16x8 vB = *(const f16x8*)(pB + 512);
    float dA = q0 * (float)kA[0] + q1 * (float)kA[1] + q2 * (float)kA[2] + q3 * (float)kA[3] +
               q4 * (float)kA[4] + q5 * (float)kA[5] + q6 * (float)kA[6] + q7 * (float)kA[7];
    float dB = q0 * (float)kB[0] + q1 * (float)kB[1] + q2 * (float)kB[2] + q3 * (float)kB[3] +
               q4 * (float)kB[4] + q5 * (float)kB[5] + q6 * (float)kB[6] + q7 * (float)kB[7];
    dA += __shfl_xor(dA, 1); dB += __shfl_xor(dB, 1);
    dA += __shfl_xor(dA, 2); dB += __shfl_xor(dB, 2);
    dA += __shfl_xor(dA, 4); dB += __shfl_xor(dB, 4);
    dA += __shfl_xor(dA, 8); dB += __shfl_xor(dB, 8);
    float aA = dA * pwA, aB = dB * pwB;
    float mn = fmaxf(m, fmaxf(aA, aB));
    float f = __expf(m - mn);
    float wA = __expf(aA - mn), wB = __expf(aB - mn);
    den = den * f + wA + wB;
    m = mn;
    o0 = o0 * f + wA * (float)vA[0] + wB * (float)vB[0];
    o1 = o1 * f + wA * (float)vA[1] + wB * (float)vB[1];
    o2 = o2 * f + wA * (float)vA[2] + wB * (float)vB[2];
    o3 = o3 * f + wA * (float)vA[3] + wB * (float)vB[3];
    o4 = o4 * f + wA * (float)vA[4] + wB * (float)vB[4];
    o5 = o5 * f + wA * (float)vA[5] + wB * (float)vB[5];
    o6 = o6 * f + wA * (float)vA[6] + wB * (float)vB[6];
    o7 = o7 * f + wA * (float)vA[7] + wB * (float)vB[7];
  }
  if (j < je) {
    int s = col_src[j];
    float pw = posw[j];
    const _Float16* p = qkv + (size_t)s * 1536 + 512 + lane * 8;
    f16x8 kv = *(const f16x8*)p;
    f16x8 vv8 = *(const f16x8*)(p + 512);
    float dot = q0 * (float)kv[0] + q1 * (float)kv[1] + q2 * (float)kv[2] + q3 * (float)kv[3] +
                q4 * (float)kv[4] + q5 * (float)kv[5] + q6 * (float)kv[6] + q7 * (float)kv[7];
    dot += __shfl_xor(dot, 1);
    dot += __shfl_xor(dot, 2);
    dot += __shfl_xor(dot, 4);
    dot += __shfl_xor(dot, 8);
    float a = dot * pw;
    float mn = fmaxf(m, a);
    float f = __expf(m - mn);
    float w = __expf(a - mn);
    den = den * f + w;
    m = mn;
    o0 = o0 * f + w * (float)vv8[0];
    o1 = o1 * f + w * (float)vv8[1];
    o2 = o2 * f + w * (float)vv8[2];
    o3 = o3 * f + w * (float)vv8[3];
    o4 = o4 * f + w * (float)vv8[4];
    o5 = o5 * f + w * (float)vv8[5];
    o6 = o6 * f + w * (float)vv8[6];
    o7 = o7 * f + w * (float)vv8[7];
  }
  if (half) {
    float* po = sO[ln] + lane * 8;
    *(float4*)(po) = make_float4(o0, o1, o2, o3);
    *(float4*)(po + 4) = make_float4(o4, o5, o6, o7);
    if ((lane & 15) == 0) { sMD[ln][head][0] = m; sMD[ln][head][1] = den; }
  }
  __syncthreads();
  if (!half) {
    float m1 = sMD[ln][head][0], d1 = sMD[ln][head][1];
    float mn = fmaxf(m, m1);
    f16x8 r;
    if (mn == -INFINITY) {
#pragma unroll
      for (int e = 0; e < 8; ++e) r[e] = (_Float16)0.f;
    } else {
      float e0 = __expf(m - mn), e1 = __expf(m1 - mn);
      float dd = den * e0 + d1 * e1;
      float inv = 1.f / (dd + 1e-16f);
      const float* po = sO[ln] + lane * 8;
      float4 p0 = *(const float4*)(po);
      float4 p1 = *(const float4*)(po + 4);
      r[0] = (_Float16)((o0 * e0 + p0.x * e1) * inv);
      r[1] = (_Float16)((o1 * e0 + p0.y * e1) * inv);
      r[2] = (_Float16)((o2 * e0 + p0.z * e1) * inv);
      r[3] = (_Float16)((o3 * e0 + p0.w * e1) * inv);
      r[4] = (_Float16)((o4 * e0 + p1.x * e1) * inv);
      r[5] = (_Float16)((o5 * e0 + p1.y * e1) * inv);
      r[6] = (_Float16)((o6 * e0 + p1.z * e1) * inv);
      r[7] = (_Float16)((o7 * e0 + p1.w * e1) * inv);
    }
    *(f16x8*)(out + (size_t)n * 512 + lane * 8) = r;
  }
}

// ---------------- MFMA f16 GEMM with global_load_lds + XOR-swizzled LDS ----------------
// C(MxN,f16) = A(MxK,f16) @ BT(NxK,f16)^T (+bias,+relu)
// BM=128, BN=64, BK=64; 256 threads = 4 waves (2x2), each wave 64x32.
// LDS physical: As[128 rows][128B], Bs[64 rows][128B]; swizzle: byte_in_row ^= ((row&7)<<4).
template <int BIAS, int RELU>
__global__ __launch_bounds__(256) void gemm_mfma(const _Float16* __restrict__ A, const _Float16* __restrict__ BT,
                                                 const float* __restrict__ bias, _Float16* __restrict__ C,
                                                 int M, int N, int K) {
  __shared__ _Float16 As[128 * 64];
  __shared__ _Float16 Bs[64 * 64];
  int tid = threadIdx.x;
  int wave = tid >> 6, lane = tid & 63;
  int l15 = lane & 15, lq = lane >> 4;
  int wr = (wave >> 1) * 64, wc = (wave & 1) * 32;
  int m0 = blockIdx.x * 128, n0 = blockIdx.y * 64;
  f32x4 acc[4][2] = {};
  int sw = (l15 & 7) << 4;
  for (int k0 = 0; k0 < K; k0 += 64) {
#pragma unroll
    for (int i = 0; i < 4; ++i) {
      int P = (wave * 4 + i) * 1024 + lane * 16;
      int row = P >> 7;
      int cl = (P & 127) ^ ((row & 7) << 4);
      int gr = m0 + row;
      if (gr > M - 1) gr = M - 1;
      const _Float16* g = A + (size_t)gr * K + k0 + (cl >> 1);
#ifdef HAS_GLL
      __builtin_amdgcn_global_load_lds((const __attribute__((address_space(1))) void*)g,
                                       (__attribute__((address_space(3))) void*)((char*)As + (wave * 4 + i) * 1024),
                                       16, 0, 0);
#else
      uint4 tv = *(const uint4*)g;
      *(uint4*)((char*)As + P) = tv;
#endif
    }
#pragma unroll
    for (int i = 0; i < 2; ++i) {
      int P = (wave * 2 + i) * 1024 + lane * 16;
      int row = P >> 7;
      int cl = (P & 127) ^ ((row & 7) << 4);
      const _Float16* g = BT + (size_t)(n0 + row) * K + k0 + (cl >> 1);
#ifdef HAS_GLL
      __builtin_amdgcn_global_load_lds((const __attribute__((address_space(1))) void*)g,
                                       (__attribute__((address_space(3))) void*)((char*)Bs + (wave * 2 + i) * 1024),
                                       16, 0, 0);
#else
      uint4 tv = *(const uint4*)g;
      *(uint4*)((char*)Bs + P) = tv;
#endif
    }
    __syncthreads();
#pragma unroll
    for (int ks = 0; ks < 2; ++ks) {
      int cc = ((ks * 32 + lq * 8) << 1) ^ sw;
      const char* pa = (const char*)As;
      const char* pb = (const char*)Bs;
      f16x8 a0 = *(const f16x8*)(pa + (wr + 0 + l15) * 128 + cc);
      f16x8 a1 = *(const f16x8*)(pa + (wr + 16 + l15) * 128 + cc);
      f16x8 a2 = *(const f16x8*)(pa + (wr + 32 + l15) * 128 + cc);
      f16x8 a3 = *(const f16x8*)(pa + (wr + 48 + l15) * 128 + cc);
      f16x8 b0 = *(const f16x8*)(pb + (wc + 0 + l15) * 128 + cc);
      f16x8 b1 = *(const f16x8*)(pb + (wc + 16 + l15) * 128 + cc);
      acc[0][0] = __builtin_amdgcn_mfma_f32_16x16x32_f16(a0, b0, acc[0][0], 0, 0, 0);
      acc[0][1] = __builtin_amdgcn_mfma_f32_16x16x32_f16(a0, b1, acc[0][1], 0, 0, 0);
      acc[1][0] = __builtin_amdgcn_mfma_f32_16x16x32_f16(a1, b0, acc[1][0], 0, 0, 0);
      acc[1][1] = __builtin_amdgcn_mfma_f32_16x16x32_f16(a1, b1, acc[1][1], 0, 0, 0);
      acc[2][0] = __builtin_amdgcn_mfma_f32_16x16x32_f16(a2, b0, acc[2][0], 0, 0, 0);
      acc[2][1] = __builtin_amdgcn_mfma_f32_16x16x32_f16(a2, b1, acc[2][1], 0, 0, 0);
      acc[3][0] = __builtin_amdgcn_mfma_f32_16x16x32_f16(a3, b0, acc[3][0], 0, 0, 0);
      acc[3][1] = __builtin_amdgcn_mfma_f32_16x16x32_f16(a3, b1, acc[3][1], 0, 0, 0);
    }
    __syncthreads();
  }
#pragma unroll
  for (int ri = 0; ri < 4; ++ri) {
    int gr0 = m0 + wr + ri * 16 + lq * 4;
#pragma unroll
    for (int ci = 0; ci < 2; ++ci) {
      int gc = n0 + wc + ci * 16 + l15;
      float bb = 0.f;
      if (BIAS) bb = bias[gc];
#pragma unroll
      for (int j = 0; j < 4; ++j) {
        int gr = gr0 + j;
        if (gr < M) {
          float x = acc[ri][ci][j] + bb;
          if (RELU) x = fmaxf(x, 0.f);
          C[(size_t)gr * N + gc] = (_Float16)x;
        }
      }
    }
  }
}

// ---------------- final tiny GEMM: (10000x256 f16) @ (256x2 f32) + b ----------------
__global__ __launch_bounds__(256) void final_kernel(const _Float16* __restrict__ X, const float* __restrict__ w3,
                                                    const float* __restrict__ b3, float* __restrict__ out) {
  int n = blockIdx.x * 256 + threadIdx.x;
  if (n >= NN) return;
  float a0 = b3[0], a1 = b3[1];
  const f16x8* xr = (const f16x8*)(X + (size_t)n * 256);
  for (int j = 0; j < 32; ++j) {
    f16x8 xv = xr[j];
#pragma unroll
    for (int e = 0; e < 8; ++e) {
      float x = (float)xv[e];
      int c = j * 8 + e;
      a0 += x * w3[c * 2 + 0];
      a1 += x * w3[c * 2 + 1];
    }
  }
  out[n * 2 + 0] = a0;
  out[n * 2 + 1] = a1;
}

extern "C" void kernel_launch(void* const* d_in, const int* in_sizes, int n_in,
                              void* d_out, int out_size, void* d_ws, size_t ws_size,
                              hipStream_t stream) {
  const float* obs = (const float*)d_in[0];
  const int* eidx = (const int*)d_in[1];
  const float* wq0 = (const float*)d_in[2];
  const float* wk0 = (const float*)d_in[3];
  const float* wv0 = (const float*)d_in[4];
  const float* wo0 = (const float*)d_in[5];
  const float* bo0 = (const float*)d_in[6];
  const float* wq1 = (const float*)d_in[7];
  const float* wk1 = (const float*)d_in[8];
  const float* wv1 = (const float*)d_in[9];
  const float* wo1 = (const float*)d_in[10];
  const float* bo1 = (const float*)d_in[11];
  const float* w1 = (const float*)d_in[12];
  const float* b1 = (const float*)d_in[13];
  const float* w2 = (const float*)d_in[14];
  const float* b2 = (const float*)d_in[15];
  const float* w3 = (const float*)d_in[16];
  const float* b3 = (const float*)d_in[17];
  float* outp = (float*)d_out;

  char* wsb = (char*)d_ws;
  _Float16* qkv = (_Float16*)(wsb + 0);          // 10000x1536
  _Float16* att = (_Float16*)(wsb + 30720000);   // 10000x512
  _Float16* h = (_Float16*)(wsb + 40960000);     // 10000x128
  _Float16* A0 = (_Float16*)(wsb + 43520000);    // 10000x64
  _Float16* wT = (_Float16*)(wsb + 44800000);    // 524288 f16
  int* counts = (int*)(wsb + 45848576);          // 10000
  int* row_start = (int*)(wsb + 45888576);       // 10001
  int* col_src = (int*)(wsb + 45928580);         // 160000
  float* posw = (float*)(wsb + 46568580);        // 160000
  _Float16* m1 = att;                            // reuse (10000x256)
  _Float16* m2 = qkv;                            // reuse (10000x256)

  _Float16* w0T = wT + 0;        // [1536][64]
  _Float16* wqkv1T = wT + 98304; // [1536][128]
  _Float16* wo0T = wT + 294912;  // [128][512]
  _Float16* wo1T = wT + 360448;  // [128][512]
  _Float16* w1T = wT + 425984;   // [256][128]
  _Float16* w2T = wT + 458752;   // [256][256]

  const int* e_src = eidx;
  const int* e_dst = eidx + NE;

  // CSR build + fused weight-convert/feature-pack
  zero_kernel<<<(NN + 255) / 256, 256, 0, stream>>>(counts, NN);
  hist_kernel<<<(NE + 255) / 256, 256, 0, stream>>>(e_dst, counts);
  prep_kernel<<<4548, 256, 0, stream>>>(wq0, wk0, wv0, wo0, wq1, wk1, wv1, wo1, w1, w2, wT, obs, A0);
  scan_kernel<<<1, 1024, 0, stream>>>(counts, row_start);
  scatter_kernel<<<(NE + 255) / 256, 256, 0, stream>>>(e_src, e_dst, obs, counts, col_src, posw);

  // layer 0
  gemm_mfma<0, 0><<<dim3(79, 24), 256, 0, stream>>>(A0, w0T, nullptr, qkv, NN, 1536, 64);
  gat_kernel<<<NN / 2, 256, 0, stream>>>(qkv, row_start, col_src, posw, att);
  gemm_mfma<1, 0><<<dim3(79, 2), 256, 0, stream>>>(att, wo0T, bo0, h, NN, 128, 512);

  // layer 1
  gemm_mfma<0, 0><<<dim3(79, 24), 256, 0, stream>>>(h, wqkv1T, nullptr, qkv, NN, 1536, 128);
  gat_kernel<<<NN / 2, 256, 0, stream>>>(qkv, row_start, col_src, posw, att);
  gemm_mfma<1, 0><<<dim3(79, 2), 256, 0, stream>>>(att, wo1T, bo1, h, NN, 128, 512);

  // MLP
  gemm_mfma<1, 1><<<dim3(79, 4), 256, 0, stream>>>(h, w1T, b1, m1, NN, 256, 128);
  gemm_mfma<1, 1><<<dim3(79, 4), 256, 0, stream>>>(m1, w2T, b2, m2, NN, 256, 256);
  final_kernel<<<(NN + 255) / 256, 256, 0, stream>>>(m2, w3, b3, outp);
}

// Round 6
// 206.499 us; speedup vs baseline: 2.4195x; 1.0357x over previous
//
#include <hip/hip_runtime.h>
#include <math.h>

#define NN 10000
#define NE 160000
#define SCALE_F 0.17677669529663687f

typedef _Float16 f16x8 __attribute__((ext_vector_type(8)));
typedef float f32x4 __attribute__((ext_vector_type(4)));

#if defined(__has_builtin)
#if __has_builtin(__builtin_amdgcn_global_load_lds)
#define HAS_GLL 1
#endif
#endif

// ---------------- CSR build ----------------
__global__ __launch_bounds__(256) void zero_kernel(int* __restrict__ p, int n) {
  int i = blockIdx.x * 256 + threadIdx.x;
  if (i < n) p[i] = 0;
}

__global__ __launch_bounds__(256) void hist_kernel(const int* __restrict__ dst, int* __restrict__ counts) {
  int e = blockIdx.x * 256 + threadIdx.x;
  if (e < NE) atomicAdd(&counts[dst[e]], 1);
}

__global__ __launch_bounds__(1024) void scan_kernel(int* __restrict__ counts, int* __restrict__ row_start) {
  __shared__ int part[1024];
  int tid = threadIdx.x;
  const int PER = 10;
  int base = tid * PER;
  int loc[PER];
  int sum = 0;
#pragma unroll
  for (int i = 0; i < PER; ++i) {
    int idx = base + i;
    int c = (idx < NN) ? counts[idx] : 0;
    loc[i] = sum;
    sum += c;
  }
  part[tid] = sum;
  __syncthreads();
  for (int off = 1; off < 1024; off <<= 1) {
    int t = (tid >= off) ? part[tid - off] : 0;
    __syncthreads();
    part[tid] += t;
    __syncthreads();
  }
  int offset = (tid > 0) ? part[tid - 1] : 0;
#pragma unroll
  for (int i = 0; i < PER; ++i) {
    int idx = base + i;
    if (idx < NN) {
      int st = offset + loc[i];
      row_start[idx] = st;
      counts[idx] = st;
    }
  }
  if (tid == 1023) row_start[NN] = part[1023];
}

__global__ __launch_bounds__(256) void scatter_kernel(const int* __restrict__ src, const int* __restrict__ dst,
                                                      const float* __restrict__ obs, int* __restrict__ cursor,
                                                      int* __restrict__ col_src, float* __restrict__ posw) {
  int e = blockIdx.x * 256 + threadIdx.x;
  if (e >= NE) return;
  int s = src[e], d = dst[e];
  int p = atomicAdd(&cursor[d], 1);
  col_src[p] = s;
  float dx = obs[d * 37 + 0] - obs[s * 37 + 0];
  float dy = obs[d * 37 + 1] - obs[s * 37 + 1];
  posw[p] = __expf(-sqrtf(dx * dx + dy * dy));
}

// ---------------- fused prep: weight transpose/convert + feature pack ----------------
__global__ __launch_bounds__(256) void prep_kernel(const float* __restrict__ wq0, const float* __restrict__ wk0,
                                                   const float* __restrict__ wv0,
                                                   const float* __restrict__ wo0, const float* __restrict__ wq1,
                                                   const float* __restrict__ wk1, const float* __restrict__ wv1,
                                                   const float* __restrict__ wo1, const float* __restrict__ w1,
                                                   const float* __restrict__ w2, _Float16* __restrict__ dst,
                                                   const float* __restrict__ obs, _Float16* __restrict__ A0) {
  int t = blockIdx.x * 256 + threadIdx.x;
  if (t >= 524288) { // pack part
    int tp = t - 524288;
    if (tp >= NN * 64) return;
    int n = tp >> 6, k = tp & 63;
    const float* o = obs + n * 37;
    float x = 0.f;
    if (k < 12) x = o[k];
    else if (k < 19) x = o[30 + k - 12];
    else if (k < 31) x = o[12 + k - 19];
    else if (k < 35) x = o[26 + k - 31];
    else if (k < 53) x = o[12 + k - 35];
    A0[tp] = (_Float16)x;
    return;
  }
  if (t < 98304) { // w0T block-diag [1536][64]
    int c = t >> 6, k = t & 63;
    float x = 0.f;
    if (c < 512) { if (k < 19) x = wq0[k * 512 + c]; }
    else if (c < 1024) { if (k >= 19 && k < 35) x = wk0[(k - 19) * 512 + (c - 512)]; }
    else { if (k >= 35 && k < 53) x = wv0[(k - 35) * 512 + (c - 1024)]; }
    dst[t] = (_Float16)x;
    return;
  }
  int t1 = t - 98304;
  if (t1 < 196608) { // wqkv1T [1536][128]
    int c = t1 >> 7, k = t1 & 127;
    float x;
    if (c < 512) x = wq1[k * 512 + c];
    else if (c < 1024) x = wk1[k * 512 + (c - 512)];
    else x = wv1[k * 512 + (c - 1024)];
    dst[98304 + t1] = (_Float16)x;
    return;
  }
  int t2 = t1 - 196608;
  if (t2 < 65536) { int n = t2 >> 9, k = t2 & 511; dst[294912 + t2] = (_Float16)wo0[k * 128 + n]; return; }
  int t3 = t2 - 65536;
  if (t3 < 65536) { int n = t3 >> 9, k = t3 & 511; dst[360448 + t3] = (_Float16)wo1[k * 128 + n]; return; }
  int t4 = t3 - 65536;
  if (t4 < 32768) { int n = t4 >> 7, k = t4 & 127; dst[425984 + t4] = (_Float16)w1[k * 256 + n]; return; }
  int t5 = t4 - 32768;
  if (t5 < 65536) { int n = t5 >> 8, k = t5 & 255; dst[458752 + t5] = (_Float16)w2[k * 256 + n]; }
}

// ---------------- fused GAT edge kernel: 2 waves per node, unroll-4, per-HEAD LDS flash-merge ----------------
// qkv layout: per node 1536 f16 = [q(512) | k(512) | v(512)]
// m/den are PER-HEAD (uniform within each 16-lane group); merge exchanges 4 (m,den) pairs per wave.
__global__ __launch_bounds__(256) void gat_kernel(const _Float16* __restrict__ qkv, const int* __restrict__ row_start,
                                                  const int* __restrict__ col_src, const float* __restrict__ posw,
                                                  _Float16* __restrict__ out) {
  __shared__ float sO[2][512];
  __shared__ float sMD[2][4][2];
  int tid = threadIdx.x;
  int wave = tid >> 6, lane = tid & 63;
  int ln = wave >> 1, half = wave & 1;
  int head = lane >> 4;
  int n = blockIdx.x * 2 + ln; // grid = NN/2 exactly
  f16x8 qv = *(const f16x8*)(qkv + (size_t)n * 1536 + lane * 8);
  float qf[8];
#pragma unroll
  for (int e = 0; e < 8; ++e) qf[e] = (float)qv[e] * SCALE_F;
  int s0 = row_start[n], s1 = row_start[n + 1];
  int mid = (s0 + s1 + 1) >> 1;
  int jb = half ? mid : s0;
  int je = half ? s1 : mid;
  float m = -INFINITY, den = 0.f;
  float o[8] = {};
  int j = jb;
  for (; j + 3 < je; j += 4) {
    int si[4];
    float pw[4];
#pragma unroll
    for (int u = 0; u < 4; ++u) { si[u] = col_src[j + u]; pw[u] = posw[j + u]; }
    f16x8 kv[4], vv4[4];
#pragma unroll
    for (int u = 0; u < 4; ++u) {
      const _Float16* p = qkv + (size_t)si[u] * 1536 + 512 + lane * 8;
      kv[u] = *(const f16x8*)p;
      vv4[u] = *(const f16x8*)(p + 512);
    }
    float d[4];
#pragma unroll
    for (int u = 0; u < 4; ++u) {
      float s = 0.f;
#pragma unroll
      for (int e = 0; e < 8; ++e) s += qf[e] * (float)kv[u][e];
      d[u] = s;
    }
#pragma unroll
    for (int x = 1; x <= 8; x <<= 1) {
#pragma unroll
      for (int u = 0; u < 4; ++u) d[u] += __shfl_xor(d[u], x);
    }
    float a[4];
#pragma unroll
    for (int u = 0; u < 4; ++u) a[u] = d[u] * pw[u];
    float m4 = fmaxf(fmaxf(a[0], a[1]), fmaxf(a[2], a[3]));
    float mn = fmaxf(m, m4);
    float f = __expf(m - mn);
    float w[4];
#pragma unroll
    for (int u = 0; u < 4; ++u) w[u] = __expf(a[u] - mn);
    den = den * f + (w[0] + w[1] + w[2] + w[3]);
    m = mn;
#pragma unroll
    for (int e = 0; e < 8; ++e)
      o[e] = o[e] * f + w[0] * (float)vv4[0][e] + w[1] * (float)vv4[1][e] +
             w[2] * (float)vv4[2][e] + w[3] * (float)vv4[3][e];
  }
  for (; j < je; ++j) {
    int s = col_src[j];
    float pw = posw[j];
    const _Float16* p = qkv + (size_t)s * 1536 + 512 + lane * 8;
    f16x8 kvs = *(const f16x8*)p;
    f16x8 vvs = *(const f16x8*)(p + 512);
    float dot = 0.f;
#pragma unroll
    for (int e = 0; e < 8; ++e) dot += qf[e] * (float)kvs[e];
    dot += __shfl_xor(dot, 1);
    dot += __shfl_xor(dot, 2);
    dot += __shfl_xor(dot, 4);
    dot += __shfl_xor(dot, 8);
    float a = dot * pw;
    float mn = fmaxf(m, a);
    float f = __expf(m - mn);
    float w = __expf(a - mn);
    den = den * f + w;
    m = mn;
#pragma unroll
    for (int e = 0; e < 8; ++e) o[e] = o[e] * f + w * (float)vvs[e];
  }
  if (half) {
    float* po = sO[ln] + lane * 8;
    *(float4*)(po) = make_float4(o[0], o[1], o[2], o[3]);
    *(float4*)(po + 4) = make_float4(o[4], o[5], o[6], o[7]);
    if ((lane & 15) == 0) { sMD[ln][head][0] = m; sMD[ln][head][1] = den; }
  }
  __syncthreads();
  if (!half) {
    float m1 = sMD[ln][head][0], d1 = sMD[ln][head][1];
    float mn = fmaxf(m, m1);
    f16x8 r;
    if (mn == -INFINITY) {
#pragma unroll
      for (int e = 0; e < 8; ++e) r[e] = (_Float16)0.f;
    } else {
      float e0 = __expf(m - mn), e1 = __expf(m1 - mn);
      float dd = den * e0 + d1 * e1;
      float inv = 1.f / (dd + 1e-16f);
      const float* po = sO[ln] + lane * 8;
      float4 p0 = *(const float4*)(po);
      float4 p1 = *(const float4*)(po + 4);
      r[0] = (_Float16)((o[0] * e0 + p0.x * e1) * inv);
      r[1] = (_Float16)((o[1] * e0 + p0.y * e1) * inv);
      r[2] = (_Float16)((o[2] * e0 + p0.z * e1) * inv);
      r[3] = (_Float16)((o[3] * e0 + p0.w * e1) * inv);
      r[4] = (_Float16)((o[4] * e0 + p1.x * e1) * inv);
      r[5] = (_Float16)((o[5] * e0 + p1.y * e1) * inv);
      r[6] = (_Float16)((o[6] * e0 + p1.z * e1) * inv);
      r[7] = (_Float16)((o[7] * e0 + p1.w * e1) * inv);
    }
    *(f16x8*)(out + (size_t)n * 512 + lane * 8) = r;
  }
}

// ---------------- MFMA f16 GEMM, double-buffered global_load_lds + XOR-swizzled LDS ----------------
// C(MxN,f16) = A(MxK,f16) @ BT(NxK,f16)^T (+bias,+relu)
// BM in {128,64}, BN=64, BK=64; 256 threads = 4 waves (2x2), wave covers (BM/2)x32.
// 2-phase pipeline: issue next K-tile GLL into buf^1, compute from buf, one __syncthreads per tile.
template <int BM, int BIAS, int RELU>
__global__ __launch_bounds__(256) void gemm_mfma(const _Float16* __restrict__ A, const _Float16* __restrict__ BT,
                                                 const float* __restrict__ bias, _Float16* __restrict__ C,
                                                 int M, int N, int K) {
  constexpr int ACH = BM / 32; // 1KB chunks per wave for A
  constexpr int WR = BM / 2;
  constexpr int RF = WR / 16;
  __shared__ _Float16 As[2][BM * 64];
  __shared__ _Float16 Bs[2][64 * 64];
  int tid = threadIdx.x;
  int wave = tid >> 6, lane = tid & 63;
  int l15 = lane & 15, lq = lane >> 4;
  int wr = (wave >> 1) * WR, wc = (wave & 1) * 32;
  int m0 = blockIdx.x * BM, n0 = blockIdx.y * 64;
  f32x4 acc[RF][2] = {};
  int sw = (l15 & 7) << 4;
  int nt = K >> 6;

  auto stage = [&](int buf, int k0) {
#pragma unroll
    for (int i = 0; i < ACH; ++i) {
      int P = (wave * ACH + i) * 1024 + lane * 16;
      int row = P >> 7;
      int cl = (P & 127) ^ ((row & 7) << 4);
      int gr = m0 + row;
      if (gr > M - 1) gr = M - 1;
      const _Float16* g = A + (size_t)gr * K + k0 + (cl >> 1);
#ifdef HAS_GLL
      __builtin_amdgcn_global_load_lds((const __attribute__((address_space(1))) void*)g,
                                       (__attribute__((address_space(3))) void*)((char*)As[buf] + (wave * ACH + i) * 1024),
                                       16, 0, 0);
#else
      uint4 tv = *(const uint4*)g;
      *(uint4*)((char*)As[buf] + P) = tv;
#endif
    }
#pragma unroll
    for (int i = 0; i < 2; ++i) {
      int P = (wave * 2 + i) * 1024 + lane * 16;
      int row = P >> 7;
      int cl = (P & 127) ^ ((row & 7) << 4);
      const _Float16* g = BT + (size_t)(n0 + row) * K + k0 + (cl >> 1);
#ifdef HAS_GLL
      __builtin_amdgcn_global_load_lds((const __attribute__((address_space(1))) void*)g,
                                       (__attribute__((address_space(3))) void*)((char*)Bs[buf] + (wave * 2 + i) * 1024),
                                       16, 0, 0);
#else
      uint4 tv = *(const uint4*)g;
      *(uint4*)((char*)Bs[buf] + P) = tv;
#endif
    }
  };

  stage(0, 0);
  __syncthreads();
  for (int t = 0; t < nt; ++t) {
    int cur = t & 1;
    if (t + 1 < nt) stage(cur ^ 1, (t + 1) << 6);
    const char* pa = (const char*)As[cur];
    const char* pb = (const char*)Bs[cur];
#pragma unroll
    for (int ks = 0; ks < 2; ++ks) {
      int cc = ((ks * 32 + lq * 8) << 1) ^ sw;
      f16x8 b0 = *(const f16x8*)(pb + (wc + 0 + l15) * 128 + cc);
      f16x8 b1 = *(const f16x8*)(pb + (wc + 16 + l15) * 128 + cc);
#pragma unroll
      for (int ri = 0; ri < RF; ++ri) {
        f16x8 a0 = *(const f16x8*)(pa + (wr + ri * 16 + l15) * 128 + cc);
        acc[ri][0] = __builtin_amdgcn_mfma_f32_16x16x32_f16(a0, b0, acc[ri][0], 0, 0, 0);
        acc[ri][1] = __builtin_amdgcn_mfma_f32_16x16x32_f16(a0, b1, acc[ri][1], 0, 0, 0);
      }
    }
    __syncthreads();
  }
#pragma unroll
  for (int ri = 0; ri < RF; ++ri) {
    int gr0 = m0 + wr + ri * 16 + lq * 4;
#pragma unroll
    for (int ci = 0; ci < 2; ++ci) {
      int gc = n0 + wc + ci * 16 + l15;
      float bb = 0.f;
      if (BIAS) bb = bias[gc];
#pragma unroll
      for (int jj = 0; jj < 4; ++jj) {
        int gr = gr0 + jj;
        if (gr < M) {
          float x = acc[ri][ci][jj] + bb;
          if (RELU) x = fmaxf(x, 0.f);
          C[(size_t)gr * N + gc] = (_Float16)x;
        }
      }
    }
  }
}

// ---------------- final tiny GEMM: (10000x256 f16) @ (256x2 f32) + b ----------------
__global__ __launch_bounds__(256) void final_kernel(const _Float16* __restrict__ X, const float* __restrict__ w3,
                                                    const float* __restrict__ b3, float* __restrict__ out) {
  int n = blockIdx.x * 256 + threadIdx.x;
  if (n >= NN) return;
  float a0 = b3[0], a1 = b3[1];
  const f16x8* xr = (const f16x8*)(X + (size_t)n * 256);
  for (int j = 0; j < 32; ++j) {
    f16x8 xv = xr[j];
#pragma unroll
    for (int e = 0; e < 8; ++e) {
      float x = (float)xv[e];
      int c = j * 8 + e;
      a0 += x * w3[c * 2 + 0];
      a1 += x * w3[c * 2 + 1];
    }
  }
  out[n * 2 + 0] = a0;
  out[n * 2 + 1] = a1;
}

extern "C" void kernel_launch(void* const* d_in, const int* in_sizes, int n_in,
                              void* d_out, int out_size, void* d_ws, size_t ws_size,
                              hipStream_t stream) {
  const float* obs = (const float*)d_in[0];
  const int* eidx = (const int*)d_in[1];
  const float* wq0 = (const float*)d_in[2];
  const float* wk0 = (const float*)d_in[3];
  const float* wv0 = (const float*)d_in[4];
  const float* wo0 = (const float*)d_in[5];
  const float* bo0 = (const float*)d_in[6];
  const float* wq1 = (const float*)d_in[7];
  const float* wk1 = (const float*)d_in[8];
  const float* wv1 = (const float*)d_in[9];
  const float* wo1 = (const float*)d_in[10];
  const float* bo1 = (const float*)d_in[11];
  const float* w1 = (const float*)d_in[12];
  const float* b1 = (const float*)d_in[13];
  const float* w2 = (const float*)d_in[14];
  const float* b2 = (const float*)d_in[15];
  const float* w3 = (const float*)d_in[16];
  const float* b3 = (const float*)d_in[17];
  float* outp = (float*)d_out;

  char* wsb = (char*)d_ws;
  _Float16* qkv = (_Float16*)(wsb + 0);          // 10000x1536
  _Float16* att = (_Float16*)(wsb + 30720000);   // 10000x512
  _Float16* h = (_Float16*)(wsb + 40960000);     // 10000x128
  _Float16* A0 = (_Float16*)(wsb + 43520000);    // 10000x64
  _Float16* wT = (_Float16*)(wsb + 44800000);    // 524288 f16
  int* counts = (int*)(wsb + 45848576);          // 10000
  int* row_start = (int*)(wsb + 45888576);       // 10001
  int* col_src = (int*)(wsb + 45928580);         // 160000
  float* posw = (float*)(wsb + 46568580);        // 160000
  _Float16* m1 = att;                            // reuse (10000x256)
  _Float16* m2 = qkv;                            // reuse (10000x256)

  _Float16* w0T = wT + 0;        // [1536][64]
  _Float16* wqkv1T = wT + 98304; // [1536][128]
  _Float16* wo0T = wT + 294912;  // [128][512]
  _Float16* wo1T = wT + 360448;  // [128][512]
  _Float16* w1T = wT + 425984;   // [256][128]
  _Float16* w2T = wT + 458752;   // [256][256]

  const int* e_src = eidx;
  const int* e_dst = eidx + NE;

  // CSR build + fused weight-convert/feature-pack
  zero_kernel<<<(NN + 255) / 256, 256, 0, stream>>>(counts, NN);
  hist_kernel<<<(NE + 255) / 256, 256, 0, stream>>>(e_dst, counts);
  prep_kernel<<<4548, 256, 0, stream>>>(wq0, wk0, wv0, wo0, wq1, wk1, wv1, wo1, w1, w2, wT, obs, A0);
  scan_kernel<<<1, 1024, 0, stream>>>(counts, row_start);
  scatter_kernel<<<(NE + 255) / 256, 256, 0, stream>>>(e_src, e_dst, obs, counts, col_src, posw);

  // layer 0
  gemm_mfma<128, 0, 0><<<dim3(79, 24), 256, 0, stream>>>(A0, w0T, nullptr, qkv, NN, 1536, 64);
  gat_kernel<<<NN / 2, 256, 0, stream>>>(qkv, row_start, col_src, posw, att);
  gemm_mfma<64, 1, 0><<<dim3(157, 2), 256, 0, stream>>>(att, wo0T, bo0, h, NN, 128, 512);

  // layer 1
  gemm_mfma<128, 0, 0><<<dim3(79, 24), 256, 0, stream>>>(h, wqkv1T, nullptr, qkv, NN, 1536, 128);
  gat_kernel<<<NN / 2, 256, 0, stream>>>(qkv, row_start, col_src, posw, att);
  gemm_mfma<64, 1, 0><<<dim3(157, 2), 256, 0, stream>>>(att, wo1T, bo1, h, NN, 128, 512);

  // MLP
  gemm_mfma<64, 1, 1><<<dim3(157, 4), 256, 0, stream>>>(h, w1T, b1, m1, NN, 256, 128);
  gemm_mfma<64, 1, 1><<<dim3(157, 4), 256, 0, stream>>>(m1, w2T, b2, m2, NN, 256, 256);
  final_kernel<<<(NN + 255) / 256, 256, 0, stream>>>(m2, w3, b3, outp);
}